// Round 6
// baseline (3510.004 us; speedup 1.0000x reference)
//
#include <hip/hip_runtime.h>
#include <math.h>

#define Bz 32
#define Tz 20
#define TMz 19
#define Vz 10000
#define INFLAT 262144   // P*D
#define RELSZ 16384
#define NBLK 512

// workspace float offsets
#define WS_PH     0
#define WS_PC     4194304
#define WS_ATT1   0              // reuses ph/pc region after k_reduce3
#define WS_EXPE   8388608        // 32768
#define WS_ZPART  8421376        // 512 (32 b x 16 pc)
#define WS_AWFP   8421888        // 16*32*256 = 131072
#define WS_GWH    8552960        // 5*6*32*256 = 245760
#define WS_GSG    8798720        // 5*32*256 = 40960
#define WS_HST    8839680        // 8192
#define WS_CST    8847872        // 8192
#define WS_CSTB   8856064        // 8192
#define WS_AT2G   8864256        // 8192
#define WS_INTS   8872448        // ordp[32] slp[32] barmem[64+512]
#define WS_PCHC   8873472        // 128*32*256 = 1048576

__device__ __forceinline__ float sigm(float x) { return 1.0f / (1.0f + expf(-x)); }

__device__ __forceinline__ void gl_lds16(const float* g, float* l) {
    __builtin_amdgcn_global_load_lds(
        (const __attribute__((address_space(1))) unsigned int*)g,
        (__attribute__((address_space(3))) unsigned int*)l,
        16, 0, 0);
}

// Slot-based grid barrier (contention-free).
__device__ __forceinline__ void gbar(int* slots, int* root, int gen) {
    __syncthreads();
    if (blockIdx.x == 0) {
        if (threadIdx.x == 0) __builtin_amdgcn_fence(__ATOMIC_RELEASE, "agent");
        int i0 = threadIdx.x;
        int i1 = threadIdx.x + 256;
        if (i0 != 0) {
            while (__hip_atomic_load(&slots[i0], __ATOMIC_RELAXED, __HIP_MEMORY_SCOPE_AGENT) < gen)
                __builtin_amdgcn_s_sleep(1);
        }
        while (__hip_atomic_load(&slots[i1], __ATOMIC_RELAXED, __HIP_MEMORY_SCOPE_AGENT) < gen)
            __builtin_amdgcn_s_sleep(1);
        __syncthreads();
        if (threadIdx.x == 0) {
            __hip_atomic_store(root, gen, __ATOMIC_RELAXED, __HIP_MEMORY_SCOPE_AGENT);
            __builtin_amdgcn_fence(__ATOMIC_ACQUIRE, "agent");
        }
    } else {
        if (threadIdx.x == 0) {
            __builtin_amdgcn_fence(__ATOMIC_RELEASE, "agent");
            __hip_atomic_store(&slots[blockIdx.x], gen, __ATOMIC_RELAXED, __HIP_MEMORY_SCOPE_AGENT);
            while (__hip_atomic_load(root, __ATOMIC_RELAXED, __HIP_MEMORY_SCOPE_AGENT) < gen)
                __builtin_amdgcn_s_sleep(2);
            __builtin_amdgcn_fence(__ATOMIC_ACQUIRE, "agent");
        }
    }
    __syncthreads();
}

// ---------------- sort + barrier init ----------------
__global__ void k_sort(const int* __restrict__ lens, float* __restrict__ out_order,
                       int* __restrict__ ord, int* __restrict__ sentlen, int* __restrict__ barmem) {
    if (threadIdx.x == 0 && blockIdx.x == 0) {
        for (int i = 0; i < 64 + NBLK; ++i) barmem[i] = 0;
        int l[Bz]; bool used[Bz];
        for (int b = 0; b < Bz; ++b) { l[b] = lens[b]; used[b] = false; }
        for (int i = 0; i < Bz; ++i) {
            int best = -1;
            for (int j = 0; j < Bz; ++j)
                if (!used[j] && (best < 0 || l[j] > l[best])) best = j;
            used[best] = true;
            ord[i] = best;
            sentlen[i] = l[best] - 1;
            out_order[i] = (float)best;
        }
    }
}

// ---------------- h0,c0: flat(32,262144) @ W_ih / W_ic ----------------
__global__ __launch_bounds__(256) void k_gemv2(const float* __restrict__ X, const int* __restrict__ ord,
                                               const float* __restrict__ W1, const float* __restrict__ W2,
                                               float* __restrict__ p1, float* __restrict__ p2) {
    __shared__ __align__(16) float wlds[8192];
    __shared__ __align__(16) float xsT[256 * 36];
    __shared__ int ords[32];
    int tid = threadIdx.x;
    int wv = tid >> 6, ln = tid & 63;
    size_t k0 = (size_t)blockIdx.x * 512;

    if (tid < 32) ords[tid] = ord[tid];
    __syncthreads();

    auto stage_xs = [&](int hh) {
        for (int idx = tid; idx < 2048; idx += 256) {
            int b = idx >> 6, kq = idx & 63;
            float4 v = *(const float4*)&X[(size_t)ords[b] * INFLAT + k0 + (size_t)hh * 256 + kq * 4];
            xsT[(kq * 4 + 0) * 36 + b] = v.x;
            xsT[(kq * 4 + 1) * 36 + b] = v.y;
            xsT[(kq * 4 + 2) * 36 + b] = v.z;
            xsT[(kq * 4 + 3) * 36 + b] = v.w;
        }
    };
    auto issue = [&](int n) {
        int slot = n & 1;
        size_t krow = k0 + (size_t)n * 8 + wv * 2;
        const float* g1 = W1 + krow * 256 + ln * 4;
        const float* g2 = W2 + krow * 256 + ln * 4;
        float* l1 = &wlds[slot * 4096 + (wv * 2) * 256 + ln * 4];
        float* l2 = &wlds[slot * 4096 + 2048 + (wv * 2) * 256 + ln * 4];
        gl_lds16(g1, l1);
        gl_lds16(g2, l2);
        gl_lds16(g1 + 256, l1 + 256);
        gl_lds16(g2 + 256, l2 + 256);
    };

    float ah[32], ac[32];
#pragma unroll
    for (int b = 0; b < 32; ++b) { ah[b] = 0.f; ac[b] = 0.f; }

    stage_xs(0);
    issue(0);

#pragma unroll 1
    for (int c = 0; c < 64; ++c) {
        if (c == 32) stage_xs(1);
        if (c + 1 < 64) {
            issue(c + 1);
            asm volatile("s_waitcnt vmcnt(4)" ::: "memory");
        } else {
            asm volatile("s_waitcnt vmcnt(0)" ::: "memory");
        }
        __syncthreads();
        int slot = c & 1;
        int xb0 = (c & 31) * 8;
#pragma unroll
        for (int kk = 0; kk < 8; ++kk) {
            float w1 = wlds[slot * 4096 + kk * 256 + tid];
            float w2 = wlds[slot * 4096 + 2048 + kk * 256 + tid];
            const float4* xr = (const float4*)&xsT[(xb0 + kk) * 36];
#pragma unroll
            for (int bq = 0; bq < 8; ++bq) {
                float4 x4 = xr[bq];
                ah[bq * 4 + 0] += x4.x * w1; ac[bq * 4 + 0] += x4.x * w2;
                ah[bq * 4 + 1] += x4.y * w1; ac[bq * 4 + 1] += x4.y * w2;
                ah[bq * 4 + 2] += x4.z * w1; ac[bq * 4 + 2] += x4.z * w2;
                ah[bq * 4 + 3] += x4.w * w1; ac[bq * 4 + 3] += x4.w * w2;
            }
        }
        __syncthreads();
    }
#pragma unroll
    for (int b = 0; b < 32; ++b) {
        size_t o = ((size_t)blockIdx.x * 32 + b) * 256 + tid;
        p1[o] = ah[b];
        p2[o] = ac[b];
    }
}

// ---------------- C0: rel(32,16384) @ W_iC, split-K ----------------
__global__ __launch_bounds__(256) void k_gemvC(const float* __restrict__ R, const int* __restrict__ ord,
                                               const float* __restrict__ W, float* __restrict__ p) {
    __shared__ float xs[32 * 128];
    __shared__ int ords[32];
    int tid = threadIdx.x, bx = blockIdx.x;
    if (tid < 32) ords[tid] = ord[tid];
    __syncthreads();
    int k0 = bx * 128;
    for (int idx = tid; idx < 32 * 128; idx += 256) {
        int b = idx >> 7, kk = idx & 127;
        xs[idx] = R[(size_t)ords[b] * RELSZ + k0 + kk];
    }
    __syncthreads();
    float acc[32];
#pragma unroll
    for (int b = 0; b < 32; ++b) acc[b] = 0.f;
    for (int kk = 0; kk < 128; ++kk) {
        float w = W[(size_t)(k0 + kk) * 256 + tid];
#pragma unroll
        for (int b = 0; b < 32; ++b) acc[b] += xs[b * 128 + kk] * w;
    }
#pragma unroll
    for (int b = 0; b < 32; ++b) p[((size_t)bx * 32 + b) * 256 + tid] = acc[b];
}

// ---------------- combined split-K reduces: h0, c0, C0 ----------------
__global__ __launch_bounds__(256) void k_reduce3(const float* __restrict__ ph, const float* __restrict__ pc,
                                                 const float* __restrict__ pC,
                                                 const float* __restrict__ b_ih, const float* __restrict__ b_ic,
                                                 const float* __restrict__ b_iC,
                                                 float* __restrict__ hst, float* __restrict__ cst,
                                                 float* __restrict__ Cst) {
    int which = blockIdx.x >> 5, b = blockIdx.x & 31, j = threadIdx.x;
    if (which == 0) {
        float s0 = b_ih[j], s1 = 0.f, s2 = 0.f, s3 = 0.f;
        for (int c = 0; c < 512; c += 4) {
            s0 += ph[((size_t)((c + 0) * 32 + b)) * 256 + j];
            s1 += ph[((size_t)((c + 1) * 32 + b)) * 256 + j];
            s2 += ph[((size_t)((c + 2) * 32 + b)) * 256 + j];
            s3 += ph[((size_t)((c + 3) * 32 + b)) * 256 + j];
        }
        hst[b * 256 + j] = s0 + s1 + s2 + s3;
    } else if (which == 1) {
        float s0 = b_ic[j], s1 = 0.f, s2 = 0.f, s3 = 0.f;
        for (int c = 0; c < 512; c += 4) {
            s0 += pc[((size_t)((c + 0) * 32 + b)) * 256 + j];
            s1 += pc[((size_t)((c + 1) * 32 + b)) * 256 + j];
            s2 += pc[((size_t)((c + 2) * 32 + b)) * 256 + j];
            s3 += pc[((size_t)((c + 3) * 32 + b)) * 256 + j];
        }
        cst[b * 256 + j] = s0 + s1 + s2 + s3;
    } else {
        float s0 = b_iC[j], s1 = 0.f, s2 = 0.f, s3 = 0.f;
        for (int c = 0; c < 128; c += 4) {
            s0 += pC[((size_t)((c + 0) * 32 + b)) * 256 + j];
            s1 += pC[((size_t)((c + 1) * 32 + b)) * 256 + j];
            s2 += pC[((size_t)((c + 2) * 32 + b)) * 256 + j];
            s3 += pC[((size_t)((c + 3) * 32 + b)) * 256 + j];
        }
        Cst[b * 256 + j] = s0 + s1 + s2 + s3;
    }
}

// ---------------- initial at2g = h0 @ W_dec + b_dec (4 blocks) ----------------
__global__ __launch_bounds__(256) void k_at2g0(const float* __restrict__ hst, const float* __restrict__ W_dec,
                                               const float* __restrict__ b_dec, float* __restrict__ at2g) {
    __shared__ __align__(16) float hs[8192];
    int tid = threadIdx.x;
    for (int i = tid; i < 2048; i += 256) ((float4*)hs)[i] = ((const float4*)hst)[i];
    __syncthreads();
    int col = blockIdx.x * 64 + (tid & 63), bg = tid >> 6;
    float acc[8] = {0.f,0.f,0.f,0.f,0.f,0.f,0.f,0.f};
    for (int k = 0; k < 256; ++k) {
        float w = W_dec[(size_t)k * 256 + col];
#pragma unroll
        for (int bi = 0; bi < 8; ++bi) acc[bi] += hs[(bg * 8 + bi) * 256 + k] * w;
    }
    float bd = b_dec[col];
#pragma unroll
    for (int bi = 0; bi < 8; ++bi) at2g[(bg * 8 + bi) * 256 + col] = acc[bi] + bd;
}

// ---------------- att1 = info_sorted @ W_enc + b_enc ----------------
__global__ __launch_bounds__(256) void k_att1(const float* __restrict__ info, const int* __restrict__ ord,
                                              const float* __restrict__ W, const float* __restrict__ bias,
                                              float* __restrict__ att1) {
    __shared__ __align__(16) float xsT[256 * 36];
    int tid = threadIdx.x;
    int r0 = blockIdx.x * 32;
    int b = r0 >> 10, p0 = r0 & 1023;
    const float* src = info + (size_t)ord[b] * INFLAT + (size_t)p0 * 256;
    for (int idx = tid; idx < 2048; idx += 256) {
        int r = idx >> 6, kq = idx & 63;
        float4 v = *(const float4*)&src[r * 256 + kq * 4];
        xsT[(kq * 4 + 0) * 36 + r] = v.x;
        xsT[(kq * 4 + 1) * 36 + r] = v.y;
        xsT[(kq * 4 + 2) * 36 + r] = v.z;
        xsT[(kq * 4 + 3) * 36 + r] = v.w;
    }
    __syncthreads();
    float acc[32];
#pragma unroll
    for (int r = 0; r < 32; ++r) acc[r] = 0.f;
    for (int k = 0; k < 256; ++k) {
        float w = W[k * 256 + tid];
        const float4* xr = (const float4*)&xsT[k * 36];
#pragma unroll
        for (int rq = 0; rq < 8; ++rq) {
            float4 x4 = xr[rq];
            acc[rq * 4 + 0] += x4.x * w;
            acc[rq * 4 + 1] += x4.y * w;
            acc[rq * 4 + 2] += x4.z * w;
            acc[rq * 4 + 3] += x4.w * w;
        }
    }
    float bj = bias[tid];
#pragma unroll
    for (int r = 0; r < 32; ++r) att1[((size_t)(r0 + r)) * 256 + tid] = acc[r] + bj;
}

// ---------------- fused steps kernel ----------------
struct KArgs {
    const float *info, *emb, *W_dec, *b_dec, *W_full, *b_full;
    const float *W_i, *W_f, *W_o, *W_g1, *W_g2;
    const float *b_i, *b_f, *b_o, *b_g1, *b_g2;
    const float *W_mlp, *b_mlp, *W_fc, *b_fc;
    const int *caps;
    float *att1, *expe, *zpart, *awfp, *gwh, *gsg, *hst, *cst, *Cst, *at2g;
    const int *ord, *slp;
    int *root, *slots;
    float *out_pred, *out_alpha;
};

// LDS (floats): PA: [0..8191] h copy | [8192..8447] at2s | [8448..8703] wf |
// [8704..12799] xb (gwh) | [12800..13055] smp | [13056..13119] exs
// PB: [0..8191] awfs | [8192..8223] invZ
// PC: [0..511] cc | [512..767] hc
__device__ void pred_task(const KArgs& a, const float* sm, int tile, int tm1) {
    int tid = threadIdx.x;
    int col = tile * 64 + (tid & 63), bg = tid >> 6;
    if (col >= Vz) return;
    float acc[8] = {0.f, 0.f, 0.f, 0.f, 0.f, 0.f, 0.f, 0.f};
    for (int jq = 0; jq < 64; ++jq) {
        float w0 = a.W_fc[(size_t)(jq * 4 + 0) * Vz + col];
        float w1 = a.W_fc[(size_t)(jq * 4 + 1) * Vz + col];
        float w2 = a.W_fc[(size_t)(jq * 4 + 2) * Vz + col];
        float w3 = a.W_fc[(size_t)(jq * 4 + 3) * Vz + col];
#pragma unroll
        for (int bi = 0; bi < 8; ++bi) {
            float4 h4 = *(const float4*)&sm[(bg * 8 + bi) * 256 + jq * 4];
            acc[bi] += h4.x * w0 + h4.y * w1 + h4.z * w2 + h4.w * w3;
        }
    }
    float bv = a.b_fc[col];
#pragma unroll
    for (int bi = 0; bi < 8; ++bi) {
        int b = bg * 8 + bi;
        float r = (a.slp[b] > tm1) ? (acc[bi] + bv) : 0.f;
        a.out_pred[((size_t)b * TMz + tm1) * Vz + col] = r;
    }
}

__device__ void gwh_task(const KArgs& a, float* sm, int tk, int t) {
    int tid = threadIdx.x;
    int g = tk / 24, r = tk % 24, ct = r / 6, ks = r % 6;
    const float* Wg = (g == 0) ? a.W_i : (g == 1) ? a.W_f : (g == 2) ? a.W_o : (g == 3) ? a.W_g1 : a.W_g2;
    int col = ct * 64 + (tid & 63), bg = tid >> 6;
    float* xb = sm + 8704;
    int wbase, hoff = 0;
    if (ks < 4) {
        wbase = ks * 128;
        for (int idx = tid; idx < 1024; idx += 256) {
            int b = idx >> 5, kq = idx & 31;
            int cap = a.caps[a.ord[b] * Tz + t];
            float4 v = *(const float4*)&a.emb[(size_t)cap * 512 + ks * 128 + kq * 4];
            *(float4*)&xb[b * 128 + kq * 4] = v;
        }
        __syncthreads();
    } else {
        wbase = 768 + (ks - 4) * 128;
        hoff = (ks - 4) * 128;
    }
    float acc[8] = {0.f, 0.f, 0.f, 0.f, 0.f, 0.f, 0.f, 0.f};
    for (int kq = 0; kq < 32; ++kq) {
        float w0 = Wg[(size_t)(wbase + kq * 4 + 0) * 256 + col];
        float w1 = Wg[(size_t)(wbase + kq * 4 + 1) * 256 + col];
        float w2 = Wg[(size_t)(wbase + kq * 4 + 2) * 256 + col];
        float w3 = Wg[(size_t)(wbase + kq * 4 + 3) * 256 + col];
#pragma unroll
        for (int bi = 0; bi < 8; ++bi) {
            int b = bg * 8 + bi;
            const float* xr = (ks < 4) ? &xb[b * 128] : &sm[b * 256 + hoff];
            float4 x4 = *(const float4*)&xr[kq * 4];
            acc[bi] += x4.x * w0 + x4.y * w1 + x4.z * w2 + x4.w * w3;
        }
    }
#pragma unroll
    for (int bi = 0; bi < 8; ++bi)
        a.gwh[((size_t)((g * 6 + ks) * 32 + bg * 8 + bi)) * 256 + col] = acc[bi];
}

__global__ __launch_bounds__(256, 2) void k_steps(KArgs a) {
    __shared__ __align__(16) float sm[13120];
    int bid = blockIdx.x, tid = threadIdx.x;
    int b = bid >> 4, sub = bid & 15;
    int gen = 0;

    for (int t = 0; t < TMz; ++t) {
        // ---------- PA: e + expe + zpart + awfp (+pred(t-1), +gwh) ----------
        bool fullh = (bid < 157) || (bid >= 392);
        if (fullh) {
            for (int i = tid; i < 2048; i += 256) ((float4*)sm)[i] = ((const float4*)a.hst)[i];
        }
        sm[8192 + tid] = a.at2g[b * 256 + tid];
        sm[8448 + tid] = a.W_full[tid];
        __syncthreads();
        {
            // e partial: thread = (pl = tid&63, kq = tid>>6), 16 indep float4 loads
            int pl = tid & 63, kq = tid >> 6;
            const float* row = a.att1 + ((size_t)(b * 1024 + sub * 64 + pl)) * 256 + kq * 64;
            const float* a2 = sm + 8192 + kq * 64;
            const float* wf = sm + 8448 + kq * 64;
            float part = 0.f;
#pragma unroll
            for (int q = 0; q < 16; ++q) {
                float4 r4 = *(const float4*)&row[q * 4];
                part += fmaxf(r4.x + a2[q * 4 + 0], 0.f) * wf[q * 4 + 0]
                      + fmaxf(r4.y + a2[q * 4 + 1], 0.f) * wf[q * 4 + 1]
                      + fmaxf(r4.z + a2[q * 4 + 2], 0.f) * wf[q * 4 + 2]
                      + fmaxf(r4.w + a2[q * 4 + 3], 0.f) * wf[q * 4 + 3];
            }
            sm[12800 + kq * 64 + pl] = part;
        }
        __syncthreads();
        if (tid < 64) {
            float e = sm[12800 + tid] + sm[12864 + tid] + sm[12928 + tid] + sm[12992 + tid] + a.b_full[0];
            float ex = expf(e);
            a.expe[b * 1024 + sub * 64 + tid] = ex;
            sm[13056 + tid] = ex;
            float s = ex;
            s += __shfl_down(s, 32); s += __shfl_down(s, 16); s += __shfl_down(s, 8);
            s += __shfl_down(s, 4);  s += __shfl_down(s, 2);  s += __shfl_down(s, 1);
            if (tid == 0) a.zpart[b * 16 + sub] = s;
        }
        __syncthreads();
        {
            // awfp: 8 independent accumulator chains
            const float* ib = a.info + (size_t)a.ord[b] * INFLAT + (size_t)(sub * 64) * 256;
            const float* ex = sm + 13056;
            float q0=0.f,q1=0.f,q2=0.f,q3=0.f,q4=0.f,q5=0.f,q6=0.f,q7=0.f;
            for (int i = 0; i < 64; i += 8) {
                q0 += ex[i+0] * ib[(size_t)(i+0) * 256 + tid];
                q1 += ex[i+1] * ib[(size_t)(i+1) * 256 + tid];
                q2 += ex[i+2] * ib[(size_t)(i+2) * 256 + tid];
                q3 += ex[i+3] * ib[(size_t)(i+3) * 256 + tid];
                q4 += ex[i+4] * ib[(size_t)(i+4) * 256 + tid];
                q5 += ex[i+5] * ib[(size_t)(i+5) * 256 + tid];
                q6 += ex[i+6] * ib[(size_t)(i+6) * 256 + tid];
                q7 += ex[i+7] * ib[(size_t)(i+7) * 256 + tid];
            }
            a.awfp[((size_t)(b * 16 + sub)) * 256 + tid] = ((q0+q1)+(q2+q3)) + ((q4+q5)+(q6+q7));
        }
        if (t > 0 && bid < 157) pred_task(a, sm, bid, t - 1);
        if (bid >= 392) gwh_task(a, sm, bid - 392, t);
        gbar(a.slots, a.root, ++gen);

        // ---------- PB: gate pre-activations (20 blocks) + alpha (32 blocks) ----------
        if (bid < 20) {
            int g = bid >> 2, ct = bid & 3;
            const float* Wg = (g == 0) ? a.W_i : (g == 1) ? a.W_f : (g == 2) ? a.W_o : (g == 3) ? a.W_g1 : a.W_g2;
            const float* bgp = (g == 0) ? a.b_i : (g == 1) ? a.b_f : (g == 2) ? a.b_o : (g == 3) ? a.b_g1 : a.b_g2;
            if (tid < 32) {
                float Z = 0.f;
#pragma unroll
                for (int c = 0; c < 16; ++c) Z += a.zpart[tid * 16 + c];
                sm[8192 + tid] = 1.0f / Z;
            }
            __syncthreads();
            // awfs[32][256] in LDS
            for (int bb = 0; bb < 32; ++bb) {
                float s0=0.f,s1=0.f;
#pragma unroll
                for (int c = 0; c < 16; c += 2) {
                    s0 += a.awfp[((size_t)(bb * 16 + c)) * 256 + tid];
                    s1 += a.awfp[((size_t)(bb * 16 + c + 1)) * 256 + tid];
                }
                sm[bb * 256 + tid] = (s0 + s1) * sm[8192 + bb];
            }
            __syncthreads();
            int col = ct * 64 + (tid & 63), bg = tid >> 6;
            float acc[8];
#pragma unroll
            for (int bi = 0; bi < 8; ++bi) {
                int bb = bg * 8 + bi;
                float s = bgp[col];
#pragma unroll
                for (int ks = 0; ks < 6; ++ks) s += a.gwh[((size_t)((g * 6 + ks) * 32 + bb)) * 256 + col];
                acc[bi] = s;
            }
            for (int kq = 0; kq < 64; ++kq) {
                float w0 = Wg[(size_t)(512 + kq * 4 + 0) * 256 + col];
                float w1 = Wg[(size_t)(512 + kq * 4 + 1) * 256 + col];
                float w2 = Wg[(size_t)(512 + kq * 4 + 2) * 256 + col];
                float w3 = Wg[(size_t)(512 + kq * 4 + 3) * 256 + col];
#pragma unroll
                for (int bi = 0; bi < 8; ++bi) {
                    const float4 x4 = *(const float4*)&sm[(bg * 8 + bi) * 256 + kq * 4];
                    acc[bi] += x4.x * w0 + x4.y * w1 + x4.z * w2 + x4.w * w3;
                }
            }
#pragma unroll
            for (int bi = 0; bi < 8; ++bi)
                a.gsg[((size_t)(g * 32 + bg * 8 + bi)) * 256 + col] = acc[bi];
        } else if (bid >= 32 && bid < 64) {
            int bb = bid - 32;
            float Z = 0.f;
#pragma unroll
            for (int c = 0; c < 16; ++c) Z += a.zpart[bb * 16 + c];
            float invZ = 1.0f / Z;
            float am = (a.slp[bb] > t) ? invZ : 0.f;
            const float* eb = a.expe + bb * 1024;
            float* oal = a.out_alpha + ((size_t)bb * TMz + t) * 1024;
            for (int p = tid; p < 1024; p += 256) oal[p] = eb[p] * am;
        }
        gbar(a.slots, a.root, ++gen);

        // ---------- PC: cell + mlp + h + at2(next) (32 blocks, one per b) ----------
        if (bid < 32) {
            int bb = bid, j = tid;
            float giv = a.gsg[((size_t)(0 * 32 + bb)) * 256 + j];
            float gfv = a.gsg[((size_t)(1 * 32 + bb)) * 256 + j];
            float gov = a.gsg[((size_t)(2 * 32 + bb)) * 256 + j];
            float gg1 = a.gsg[((size_t)(3 * 32 + bb)) * 256 + j];
            float gg2 = a.gsg[((size_t)(4 * 32 + bb)) * 256 + j];
            float iv = sigm(giv), fv = sigm(gfv), ov = sigm(gov);
            float g1 = tanhf(gg1), g2 = tanhf(gg2);
            float nc = fv * a.cst[bb * 256 + j] + iv * g1;
            float nC = fv * a.Cst[bb * 256 + j] + iv * g2;
            a.cst[bb * 256 + j] = nc;
            a.Cst[bb * 256 + j] = nC;
            sm[j] = nc;
            sm[256 + j] = nC;
            __syncthreads();
            float m0 = a.b_mlp[j], m1=0.f, m2=0.f, m3=0.f, m4=0.f, m5=0.f, m6=0.f, m7=0.f;
            for (int k = 0; k < 512; k += 8) {
                m0 += sm[k+0] * a.W_mlp[(size_t)(k+0) * 256 + j];
                m1 += sm[k+1] * a.W_mlp[(size_t)(k+1) * 256 + j];
                m2 += sm[k+2] * a.W_mlp[(size_t)(k+2) * 256 + j];
                m3 += sm[k+3] * a.W_mlp[(size_t)(k+3) * 256 + j];
                m4 += sm[k+4] * a.W_mlp[(size_t)(k+4) * 256 + j];
                m5 += sm[k+5] * a.W_mlp[(size_t)(k+5) * 256 + j];
                m6 += sm[k+6] * a.W_mlp[(size_t)(k+6) * 256 + j];
                m7 += sm[k+7] * a.W_mlp[(size_t)(k+7) * 256 + j];
            }
            float hv = ov * tanhf(((m0+m1)+(m2+m3)) + ((m4+m5)+(m6+m7)));
            a.hst[bb * 256 + j] = hv;
            sm[512 + j] = hv;
            __syncthreads();
            // at2 for next step
            float a0 = a.b_dec[j], a1=0.f, a2=0.f, a3=0.f, a4=0.f, a5=0.f, a6=0.f, a7=0.f;
            for (int k = 0; k < 256; k += 8) {
                a0 += sm[512 + k+0] * a.W_dec[(size_t)(k+0) * 256 + j];
                a1 += sm[512 + k+1] * a.W_dec[(size_t)(k+1) * 256 + j];
                a2 += sm[512 + k+2] * a.W_dec[(size_t)(k+2) * 256 + j];
                a3 += sm[512 + k+3] * a.W_dec[(size_t)(k+3) * 256 + j];
                a4 += sm[512 + k+4] * a.W_dec[(size_t)(k+4) * 256 + j];
                a5 += sm[512 + k+5] * a.W_dec[(size_t)(k+5) * 256 + j];
                a6 += sm[512 + k+6] * a.W_dec[(size_t)(k+6) * 256 + j];
                a7 += sm[512 + k+7] * a.W_dec[(size_t)(k+7) * 256 + j];
            }
            a.at2g[bb * 256 + j] = ((a0+a1)+(a2+a3)) + ((a4+a5)+(a6+a7));
        }
        gbar(a.slots, a.root, ++gen);
    }

    // epilogue: pred for t = 18
    if (bid < 157) {
        for (int i = tid; i < 2048; i += 256) ((float4*)sm)[i] = ((const float4*)a.hst)[i];
        __syncthreads();
        pred_task(a, sm, bid, TMz - 1);
    }
}

extern "C" void kernel_launch(void* const* d_in, const int* in_sizes, int n_in,
                              void* d_out, int out_size, void* d_ws, size_t ws_size,
                              hipStream_t stream) {
    const float* info  = (const float*)d_in[0];
    const float* rel   = (const float*)d_in[1];
    const int*   caps  = (const int*)d_in[2];
    const int*   lens  = (const int*)d_in[3];
    const float* emb   = (const float*)d_in[4];
    const float* W_enc = (const float*)d_in[5];
    const float* b_enc = (const float*)d_in[6];
    const float* W_dec = (const float*)d_in[7];
    const float* b_dec = (const float*)d_in[8];
    const float* W_full= (const float*)d_in[9];
    const float* b_full= (const float*)d_in[10];
    const float* W_i   = (const float*)d_in[11];
    const float* b_i   = (const float*)d_in[12];
    const float* W_f   = (const float*)d_in[13];
    const float* b_f   = (const float*)d_in[14];
    const float* W_o   = (const float*)d_in[15];
    const float* b_o   = (const float*)d_in[16];
    const float* W_g1  = (const float*)d_in[17];
    const float* b_g1  = (const float*)d_in[18];
    const float* W_g2  = (const float*)d_in[19];
    const float* b_g2  = (const float*)d_in[20];
    const float* W_mlp = (const float*)d_in[21];
    const float* b_mlp = (const float*)d_in[22];
    const float* W_fc  = (const float*)d_in[25];
    const float* b_fc  = (const float*)d_in[26];
    const float* W_ih  = (const float*)d_in[27];
    const float* b_ih  = (const float*)d_in[28];
    const float* W_ic  = (const float*)d_in[29];
    const float* b_ic  = (const float*)d_in[30];
    const float* W_iC  = (const float*)d_in[31];
    const float* b_iC  = (const float*)d_in[32];

    float* out = (float*)d_out;
    float* out_pred  = out;
    float* out_alpha = out + (size_t)Bz * TMz * Vz;
    float* out_order = out_alpha + (size_t)Bz * TMz * 1024;

    float* w = (float*)d_ws;
    float* ph   = w + WS_PH;
    float* pcp  = w + WS_PC;
    float* att1 = w + WS_ATT1;
    float* expe = w + WS_EXPE;
    float* zpart= w + WS_ZPART;
    float* awfp = w + WS_AWFP;
    float* gwh  = w + WS_GWH;
    float* gsg  = w + WS_GSG;
    float* hst  = w + WS_HST;
    float* cst  = w + WS_CST;
    float* Cst  = w + WS_CSTB;
    float* at2g = w + WS_AT2G;
    int*   ordp = (int*)(w + WS_INTS);
    int*   slp  = ordp + 32;
    int*   barmem = ordp + 64;
    float* pC   = w + WS_PCHC;

    k_sort<<<1, 64, 0, stream>>>(lens, out_order, ordp, slp, barmem);
    k_gemv2<<<512, 256, 0, stream>>>(info, ordp, W_ih, W_ic, ph, pcp);
    k_gemvC<<<128, 256, 0, stream>>>(rel, ordp, W_iC, pC);
    k_reduce3<<<96, 256, 0, stream>>>(ph, pcp, pC, b_ih, b_ic, b_iC, hst, cst, Cst);
    k_at2g0<<<4, 256, 0, stream>>>(hst, W_dec, b_dec, at2g);
    k_att1<<<1024, 256, 0, stream>>>(info, ordp, W_enc, b_enc, att1);

    KArgs ka;
    ka.info = info; ka.emb = emb; ka.W_dec = W_dec; ka.b_dec = b_dec;
    ka.W_full = W_full; ka.b_full = b_full;
    ka.W_i = W_i; ka.W_f = W_f; ka.W_o = W_o; ka.W_g1 = W_g1; ka.W_g2 = W_g2;
    ka.b_i = b_i; ka.b_f = b_f; ka.b_o = b_o; ka.b_g1 = b_g1; ka.b_g2 = b_g2;
    ka.W_mlp = W_mlp; ka.b_mlp = b_mlp; ka.W_fc = W_fc; ka.b_fc = b_fc;
    ka.caps = caps;
    ka.att1 = att1; ka.expe = expe; ka.zpart = zpart; ka.awfp = awfp; ka.gwh = gwh;
    ka.gsg = gsg; ka.hst = hst; ka.cst = cst; ka.Cst = Cst; ka.at2g = at2g;
    ka.ord = ordp; ka.slp = slp;
    ka.root = barmem; ka.slots = barmem + 64;
    ka.out_pred = out_pred; ka.out_alpha = out_alpha;

    k_steps<<<NBLK, 256, 0, stream>>>(ka);
}